// Round 10
// baseline (516.735 us; speedup 1.0000x reference)
//
#include <hip/hip_runtime.h>
#include <hip/hip_cooperative_groups.h>
namespace cg = cooperative_groups;

typedef unsigned char u8;

#define NUM_IDS 65
#define EDIM 32
#define NSUM (NUM_IDS * EDIM)      // 2080
#define NTOT (NSUM + NUM_IDS)      // 2145
#define LPAD 33                    // mean tile row pad
#define ROWS 34                    // phase-A row: 32 sums + count + pad
#define COPYSZ 2212                // 65*34 -> pad even
#define NB 1024                    // 4 blocks/CU * 256 CUs (co-resident)
#define K2BLK ((NTOT + 31) / 32)   // 68
#define CO 2208                    // coef offset inside ls (floats)

// ws float offsets
#define WS_SUMS    0               // 2145
#define WS_PUSH    2145
#define WS_REG     2146
#define WS_CF      2147
#define WS_C       2148
#define WS_PULLACC 2149
#define WS_PART    2176            // [NB][NTOT] per-block partials

__global__ __launch_bounds__(256, 4) void kfused(
    const float2* __restrict__ emb2, const int* __restrict__ lab,
    float* __restrict__ ws, float* __restrict__ out, int M)
{
    __shared__ float ls[4 * COPYSZ];        // phase A: 4 wave-private sum copies; phase B/C: means+coef
    __shared__ u8    llab[1984];            // span labels (stashed in pass 1, reused in pass 2)
    __shared__ float lpull[4][NUM_IDS];
    __shared__ float red[256], red2[256];
    __shared__ int   lpres[NUM_IDS];

    const int t = threadIdx.x, b = blockIdx.x;
    const int wave = t >> 6, lane = t & 63;
    const int s = lane >> 4, c = lane & 15;  // phase A: 4 pt-slots x 16 lanes (float2)
    float* my = ls + wave * COPYSZ;
    cg::grid_group grid = cg::this_grid();

    for (int j = t; j < 4 * COPYSZ; j += 256) ls[j] = 0.f;
    for (int j = t; j < 4 * NUM_IDS; j += 256) lpull[j / NUM_IDS][j % NUM_IDS] = 0.f;
    __syncthreads();

    const int TC = (M + 15) / 16;            // 16-pt chunks
    const int Q = TC / NB, R = TC - Q * NB;
    const int cs = b * Q + (b < R ? b : R);  // block-contiguous span
    const int cnt = Q + (b < R ? 1 : 0);     // <=123 chunks -> <=1968 pts
    const long pbase = (long)cs * 16;

    // ---------------- phase A: segment sums + counts ----------------
    auto LD = [&](int i, int& L, float2& v) {
        L = 0; v = make_float2(0.f, 0.f);
        if (i < cnt) {
            int idx = i * 16 + wave * 4 + s;
            long p = pbase + idx;
            if (p < M) { L = lab[p]; v = emb2[p * 16 + c]; }
            if (c == 0) llab[idx] = (u8)L;
        }
    };
    auto PR = [&](int i, int L, float2 v) {
        if (i >= cnt) return;
        const bool act = (L > 0);
        int key = act ? L : (-1 - s);        // unique negatives never collide
        int k0 = __shfl(key, c);
        int k1 = __shfl(key, 16 + c);
        int k2 = __shfl(key, 32 + c);
        int k3 = __shfl(key, 48 + c);
        bool col = (k0 == k1) | (k0 == k2) | (k0 == k3) |
                   (k1 == k2) | (k1 == k3) | (k2 == k3);
        float sx = v.x, sy = v.y, cnt1 = 1.f;
        bool writer = act;
        if (col) {                            // wave-uniform, ~9%: in-register merge
            int c1 = (k1 == k0) ? 0 : 1;
            int c2 = (k2 == k0) ? 0 : ((k2 == k1) ? 1 : 2);
            int c3 = (k3 == k0) ? 0 : ((k3 == k1) ? 1 : ((k3 == k2) ? 2 : 3));
            float x0 = __shfl(v.x, c),      y0 = __shfl(v.y, c);
            float x1 = __shfl(v.x, 16 + c), y1 = __shfl(v.y, 16 + c);
            float x2 = __shfl(v.x, 32 + c), y2 = __shfl(v.y, 32 + c);
            float x3 = __shfl(v.x, 48 + c), y3 = __shfl(v.y, 48 + c);
            sx = 0.f; sy = 0.f; cnt1 = 0.f;
            if (0 == s)  { sx += x0; sy += y0; cnt1 += 1.f; }
            if (c1 == s) { sx += x1; sy += y1; cnt1 += 1.f; }
            if (c2 == s) { sx += x2; sy += y2; cnt1 += 1.f; }
            if (c3 == s) { sx += x3; sy += y3; cnt1 += 1.f; }
            int csl = (s == 0) ? 0 : (s == 1) ? c1 : (s == 2) ? c2 : c3;
            writer = act && (csl == s);       // canonical slot writes merged sum
        }
        if (writer) {
            int off = L * ROWS + 2 * c;
            float2 o = *(float2*)(my + off);
            o.x += sx; o.y += sy;
            *(float2*)(my + off) = o;
            if (c == 0) my[L * ROWS + 32] += cnt1;
        }
    };

    {   // ping-pong, named registers
        int L0, L1; float2 v0, v1;
        LD(0, L0, v0);
        for (int i = 0; i < cnt; i += 2) {
            LD(i + 1, L1, v1);
            PR(i, L0, v0);
            LD(i + 2, L0, v0);
            PR(i + 1, L1, v1);
        }
    }
    __syncthreads();
    for (int j = t; j < NTOT; j += 256) {     // flush 4 copies -> per-block partials
        int off = (j < NSUM) ? ((j >> 5) * ROWS + (j & 31))
                             : ((j - NSUM) * ROWS + 32);
        ws[WS_PART + (size_t)b * NTOT + j] =
            ls[off] + ls[COPYSZ + off] + ls[2 * COPYSZ + off] + ls[3 * COPYSZ + off];
    }
    grid.sync();

    // ---------------- phase B1: reduce partials (blocks 0..67) ----------------
    if (b < K2BLK) {
        const int jl = t & 31, bl = t >> 5;
        const int j = b * 32 + jl;
        float acc = 0.f;
        if (j < NTOT)
            for (int r = bl; r < NB; r += 8) acc += ws[WS_PART + (size_t)r * NTOT + j];
        red[t] = acc;
        __syncthreads();
        for (int sd = 128; sd >= 32; sd >>= 1) { if (t < sd) red[t] += red[t + sd]; __syncthreads(); }
        if (t < 32) { int jj = b * 32 + t; if (jj < NTOT) ws[WS_SUMS + jj] = red[t]; }
    }
    if (b == K2BLK && t == 0) ws[WS_PULLACC] = 0.f;
    grid.sync();

    // ---------------- phase B2: every block builds means+coef in LDS ----------------
    for (int j = t; j < NSUM; j += 256) {
        int cc = j >> 5, e = j & 31;
        ls[cc * LPAD + e] = ws[WS_SUMS + j] / fmaxf(ws[WS_SUMS + NSUM + cc], 1.f);
    }
    if (t < NUM_IDS) {
        float cv = ws[WS_SUMS + NSUM + t];
        int pres = (t > 0 && cv > 0.f) ? 1 : 0;
        lpres[t] = pres;
        ls[CO + t] = pres ? (1.f / fmaxf(cv, 1.f)) : 0.f;
    }
    __syncthreads();

    if (b == 0) {   // push + reg on block 0 only
        float psum = 0.f;
        for (int pi = t; pi < 2080; pi += 256) {
            int i = 0, rem = pi;
            while (rem >= NUM_IDS - 1 - i) { rem -= NUM_IDS - 1 - i; ++i; }
            int jj = i + 1 + rem;
            if (lpres[i] && lpres[jj]) {
                float d2 = 0.f;
                #pragma unroll
                for (int e = 0; e < EDIM; ++e) {
                    float d = ls[i * LPAD + e] - ls[jj * LPAD + e];
                    d2 += d * d;
                }
                float pd = sqrtf(d2);
                float h = fmaxf(3.0f - pd, 0.f);      // 2*DELTA_PUSH
                psum += h * h;
            }
        }
        float rsum = 0.f;
        if (t < NUM_IDS && lpres[t]) {
            float m2 = 0.f;
            #pragma unroll
            for (int e = 0; e < EDIM; ++e) { float m = ls[t * LPAD + e]; m2 += m * m; }
            rsum = sqrtf(m2);
        }
        red[t] = psum; red2[t] = rsum;
        __syncthreads();
        for (int sd = 128; sd > 0; sd >>= 1) {
            if (t < sd) { red[t] += red[t + sd]; red2[t] += red2[t + sd]; }
            __syncthreads();
        }
        if (t == 0) {
            int C = 0;
            for (int cc = 1; cc < NUM_IDS; ++cc) C += lpres[cc];
            float Cf = fmaxf((float)C, 1.f);
            long np = (long)C * (C - 1) / 2;
            ws[WS_PUSH] = (np > 0) ? red[0] / (float)np : 0.f;
            ws[WS_REG]  = red2[0] / Cf;
            ws[WS_CF]   = Cf;
            ws[WS_C]    = (float)C;
        }
    }

    // ---------------- phase C: pull pass over same span (labels from LDS) ----------------
    {
        const float4* e4 = (const float4*)emb2;
        const int s4 = lane >> 3, c4 = lane & 7;   // 8 pts x 8 lanes (float4)
        const int G = 2 * cnt;                     // 8-pt groups in span
        auto LD4 = [&](int i2, int& L, float4& v) {
            L = 0; v = make_float4(0.f, 0.f, 0.f, 0.f);
            if (i2 < G) {
                int idx = i2 * 8 + s4;
                long p = pbase + idx;
                if (p < M) { L = llab[idx]; v = e4[p * 8 + c4]; }
            }
        };
        auto PR4 = [&](int i2, int L, float4 v) {
            if (i2 >= G) return;
            float d2 = 0.f;
            if (L > 0) {
                int bse = L * LPAD + c4 * 4;
                float dx = v.x - ls[bse + 0];
                float dy = v.y - ls[bse + 1];
                float dz = v.z - ls[bse + 2];
                float dw = v.w - ls[bse + 3];
                d2 = dx * dx + dy * dy + dz * dz + dw * dw;
            }
            d2 += __shfl_xor(d2, 1);
            d2 += __shfl_xor(d2, 2);
            d2 += __shfl_xor(d2, 4);
            if (c4 == 0 && L > 0 && d2 > 0.f) {
                float dist = sqrtf(d2);
                float h = fmaxf(dist - 0.5f, 0.f);   // DELTA_PULL
                atomicAdd(&lpull[wave][L], h * h);
            }
        };
        int La, Lb; float4 va, vb;
        LD4(wave, La, va);
        for (int i2 = wave; i2 < G; i2 += 8) {       // waves split groups mod 4; 2/iter
            LD4(i2 + 4, Lb, vb);
            PR4(i2, La, va);
            LD4(i2 + 8, La, va);
            PR4(i2 + 4, Lb, vb);
        }
    }
    __syncthreads();
    {
        float pv = 0.f;
        if (t > 0 && t < NUM_IDS)
            pv = (lpull[0][t] + lpull[1][t] + lpull[2][t] + lpull[3][t]) * ls[CO + t];
        red[t] = (t < NUM_IDS) ? pv : 0.f;
        __syncthreads();
        for (int sd = 128; sd > 0; sd >>= 1) { if (t < sd) red[t] += red[t + sd]; __syncthreads(); }
        if (t == 0 && red[0] != 0.f) atomicAdd(&ws[WS_PULLACC], red[0]);
    }
    grid.sync();

    if (b == 0 && t == 0) {
        float C = ws[WS_C];
        out[0] = (C > 0.f)
            ? ws[WS_PULLACC] / ws[WS_CF] + ws[WS_PUSH] + 0.001f * ws[WS_REG]
            : 0.f;
    }
}

extern "C" void kernel_launch(void* const* d_in, const int* in_sizes, int n_in,
                              void* d_out, int out_size, void* d_ws, size_t ws_size,
                              hipStream_t stream) {
    const float2* emb2 = (const float2*)d_in[0];
    const int* lab = (const int*)d_in[1];
    float* ws = (float*)d_ws;
    float* out = (float*)d_out;
    int M = in_sizes[1];
    void* args[] = { (void*)&emb2, (void*)&lab, (void*)&ws, (void*)&out, (void*)&M };
    hipLaunchCooperativeKernel((const void*)kfused, dim3(NB), dim3(256), args, 0, stream);
}

// Round 11
// 169.039 us; speedup vs baseline: 3.0569x; 3.0569x over previous
//
#include <hip/hip_runtime.h>

#define NUM_IDS 65
#define EDIM 32
#define NSUM (NUM_IDS * EDIM)      // 2080
#define NTOT (NSUM + NUM_IDS)      // 2145
#define LPAD 33                    // k3/k4 mean tile row pad
#define R36 36                     // k1 accum row: 32 sums + count + pad; 144B -> b128-aligned rows
#define CP (NUM_IDS * R36)         // 2340 floats per wave copy

// ws float offsets
#define WS_MEANS   0               // 2080
#define WS_COEF    2080            // 65
#define WS_SUMS    2145            // 2145
#define WS_PUSH    4290
#define WS_REG     4291
#define WS_CF      4292
#define WS_C       4293
#define WS_PULLACC 4294
#define WS_PART    4352            // [nb1][NTOT]

__global__ void k0_zero(float* __restrict__ ws) {
    int i = blockIdx.x * 256 + threadIdx.x;
    if (i < NTOT) ws[WS_SUMS + i] = 0.f;
}

// Pass 1: wave-private LDS segment reduction, 8 slots x 8 lanes (float4/lane).
// Chain-optimized: early accumulator read, no value shuffles (multi-round
// exec-masked RMW for duplicate labels), counts in registers.
__global__ __launch_bounds__(256) void k1_reduce(const float4* __restrict__ emb4,
                                                 const int* __restrict__ lab,
                                                 float* __restrict__ ws,
                                                 int M, int nb1, int atomic_mode) {
    __shared__ float ls[4 * CP];               // 37.4 KB -> 4 blocks/CU
    const int t = threadIdx.x;
    const int wave = t >> 6, lane = t & 63;
    const int s = lane >> 3;                   // point slot 0..7
    const int c = lane & 7;                    // float4 chunk (dims 4c..4c+3)
    float* my = ls + wave * CP;
    for (int j = t; j < 4 * CP; j += 256) ls[j] = 0.f;
    __syncthreads();

    float cntreg = 0.f;                        // count for label lane+1 (1..64)
    const int lp1 = lane + 1;

    const long stride = (long)nb1 * 32;        // 32 pts per block-iter
    const long p0 = (long)blockIdx.x * 32 + wave * 8 + s;

    auto LD = [&](long p, int& L, float4& v) {
        if (p < M) { L = lab[p]; v = emb4[p * 8 + c]; }
        else       { L = 0; v = make_float4(0.f, 0.f, 0.f, 0.f); }
    };

    auto PR = [&](int L, float4 v) {
        const int off = L * R36 + 4 * c;
        float4 old = *(float4*)(my + off);     // EARLY: hides under shuffle wait
        const bool act = (L > 0);
        int key = act ? L : (-64 - s);         // unique negatives never collide
        int q0 = __shfl(key, 0 + c),  q1 = __shfl(key, 8 + c);
        int q2 = __shfl(key, 16 + c), q3 = __shfl(key, 24 + c);
        int q4 = __shfl(key, 32 + c), q5 = __shfl(key, 40 + c);
        int q6 = __shfl(key, 48 + c), q7 = __shfl(key, 56 + c);
        // in-register counts (q_j are wave-uniform slot labels)
        cntreg += (float)((q0 == lp1) + (q1 == lp1) + (q2 == lp1) + (q3 == lp1) +
                          (q4 == lp1) + (q5 == lp1) + (q6 == lp1) + (q7 == lp1));
        // ne = # earlier slots with same label (0 => canonical writer)
        int ne = 0;
        ne += (0 < s && q0 == key); ne += (1 < s && q1 == key);
        ne += (2 < s && q2 == key); ne += (3 < s && q3 == key);
        ne += (4 < s && q4 == key); ne += (5 < s && q5 == key);
        ne += (6 < s && q6 == key);
        if (act && ne == 0) {
            float4 nv; nv.x = old.x + v.x; nv.y = old.y + v.y;
            nv.z = old.z + v.z; nv.w = old.w + v.w;
            *(float4*)(my + off) = nv;
        }
        if (__ballot(act && ne > 0)) {         // rare: duplicate labels in wave
            #pragma unroll 1
            for (int r = 1; r < 8; ++r) {      // ne values are downward-closed
                if (!__ballot(act && ne == r)) break;
                if (act && ne == r) {          // in-order DS: sees round r-1 write
                    float4 o2 = *(float4*)(my + off);
                    o2.x += v.x; o2.y += v.y; o2.z += v.z; o2.w += v.w;
                    *(float4*)(my + off) = o2;
                }
            }
        }
    };

    int La, Lb; float4 va, vb;
    long pA = p0;
    LD(pA, La, va);
    while (pA < M) {
        const long pB = pA + stride;
        LD(pB, Lb, vb);
        PR(La, va);
        const long pA2 = pB + stride;
        LD(pA2, La, va);
        PR(Lb, vb);
        pA = pA2;
    }

    my[lp1 * R36 + 32] += cntreg;              // flush register counts (labels 1..64)
    __syncthreads();

    for (int j = t; j < NTOT; j += 256) {      // combine 4 wave copies
        int off = (j < NSUM) ? ((j >> 5) * R36 + (j & 31))
                             : ((j - NSUM) * R36 + 32);
        float v = ls[off] + ls[CP + off] + ls[2 * CP + off] + ls[3 * CP + off];
        if (atomic_mode) {
            if (v != 0.f) atomicAdd(&ws[WS_SUMS + j], v);
        } else {
            ws[WS_PART + (size_t)blockIdx.x * NTOT + j] = v;
        }
    }
}

// Reduce per-block partials: 32 consecutive j per block, 8 b-lanes per j.
__global__ __launch_bounds__(256) void k2_reduce_partials(float* __restrict__ ws, int nb1) {
    const int t = threadIdx.x;
    const int jl = t & 31, bl = t >> 5;
    const int j = blockIdx.x * 32 + jl;
    const float* part = ws + WS_PART;
    float acc = 0.f;
    if (j < NTOT)
        for (int b = bl; b < nb1; b += 8) acc += part[(size_t)b * NTOT + j];
    __shared__ float red[256];
    red[t] = acc;
    __syncthreads();
    for (int sd = 128; sd >= 32; sd >>= 1) {
        if (t < sd) red[t] += red[t + sd];
        __syncthreads();
    }
    if (t < 32) {
        int jj = blockIdx.x * 32 + t;
        if (jj < NTOT) ws[WS_SUMS + jj] = red[t];
    }
}

// Means, present, C, push, reg, coef; zero pull accumulator.
__global__ __launch_bounds__(256) void k3_finalize(float* __restrict__ ws) {
    __shared__ float lmean[NUM_IDS * LPAD];
    __shared__ float lcnt[NUM_IDS];
    __shared__ int   lpres[NUM_IDS];
    __shared__ float red[256];
    __shared__ float red2[256];
    const int t = threadIdx.x;
    const float* sg = ws + WS_SUMS;

    if (t < NUM_IDS) {
        float cv = sg[NSUM + t];
        lcnt[t] = cv;
        lpres[t] = (t > 0 && cv > 0.f) ? 1 : 0;
    }
    __syncthreads();

    for (int j = t; j < NSUM; j += 256) {
        int cc = j >> 5, e = j & 31;
        float m = sg[j] / fmaxf(lcnt[cc], 1.f);
        ws[WS_MEANS + j] = m;
        lmean[cc * LPAD + e] = m;
    }
    if (t < NUM_IDS) ws[WS_COEF + t] = lpres[t] ? (1.f / fmaxf(lcnt[t], 1.f)) : 0.f;
    __syncthreads();

    float psum = 0.f;
    for (int pi = t; pi < 2080; pi += 256) {
        int i = 0, rem = pi;
        while (rem >= NUM_IDS - 1 - i) { rem -= NUM_IDS - 1 - i; ++i; }
        int jj = i + 1 + rem;
        if (lpres[i] && lpres[jj]) {
            float d2 = 0.f;
            #pragma unroll
            for (int e = 0; e < EDIM; ++e) {
                float d = lmean[i * LPAD + e] - lmean[jj * LPAD + e];
                d2 += d * d;
            }
            float pd = sqrtf(d2);
            float h = fmaxf(3.0f - pd, 0.f);   // 2*DELTA_PUSH
            psum += h * h;
        }
    }
    float rsum = 0.f;
    if (t < NUM_IDS && lpres[t]) {
        float m2 = 0.f;
        #pragma unroll
        for (int e = 0; e < EDIM; ++e) { float m = lmean[t * LPAD + e]; m2 += m * m; }
        rsum = sqrtf(m2);
    }
    red[t] = psum; red2[t] = rsum;
    __syncthreads();
    for (int sd = 128; sd > 0; sd >>= 1) {
        if (t < sd) { red[t] += red[t + sd]; red2[t] += red2[t + sd]; }
        __syncthreads();
    }
    if (t == 0) {
        int C = 0;
        for (int cc = 1; cc < NUM_IDS; ++cc) C += lpres[cc];
        float Cf = fmaxf((float)C, 1.f);
        long np = (long)C * (C - 1) / 2;
        ws[WS_PUSH] = (np > 0) ? red[0] / (float)np : 0.f;
        ws[WS_REG]  = red2[0] / Cf;
        ws[WS_CF]   = Cf;
        ws[WS_C]    = (float)C;
        ws[WS_PULLACC] = 0.f;
    }
}

// Pass 2: hinged pull distances; ping-pong pipelined loads (L3-fed after k1).
__global__ __launch_bounds__(256) void k4_pull(const float4* __restrict__ emb4,
                                               const int* __restrict__ lab,
                                               float* __restrict__ ws,
                                               int M, int nb4) {
    __shared__ float lmean[NUM_IDS * LPAD];
    __shared__ float lcoef[NUM_IDS];
    __shared__ float lpull[NUM_IDS];
    __shared__ float red[NUM_IDS];
    const int t = threadIdx.x;
    for (int j = t; j < NSUM; j += 256) lmean[(j >> 5) * LPAD + (j & 31)] = ws[WS_MEANS + j];
    if (t < NUM_IDS) { lcoef[t] = ws[WS_COEF + t]; lpull[t] = 0.f; }
    __syncthreads();

    const int c = t & 7;
    const long stride = (long)nb4 * 32;
    const long start = (long)blockIdx.x * 32 + (t >> 3);

    auto LD = [&](long p, int& L, float4& v) {
        if (p < M) { L = lab[p]; v = emb4[p * 8 + c]; }
        else       { L = 0; v = make_float4(0.f, 0.f, 0.f, 0.f); }
    };
    auto PR = [&](int L, float4 v) {
        float d2 = 0.f;
        if (L > 0) {
            int bse = L * LPAD + c * 4;
            float dx = v.x - lmean[bse + 0];
            float dy = v.y - lmean[bse + 1];
            float dz = v.z - lmean[bse + 2];
            float dw = v.w - lmean[bse + 3];
            d2 = dx * dx + dy * dy + dz * dz + dw * dw;
        }
        d2 += __shfl_xor(d2, 1);
        d2 += __shfl_xor(d2, 2);
        d2 += __shfl_xor(d2, 4);
        if (c == 0 && L > 0 && d2 > 0.f) {
            float dist = sqrtf(d2);
            float h = fmaxf(dist - 0.5f, 0.f);   // DELTA_PULL
            atomicAdd(&lpull[L], h * h);
        }
    };

    int L0, L1;
    float4 v0, v1;
    long pA = start;
    LD(pA, L0, v0);
    while (pA < M) {
        const long pB = pA + stride;
        LD(pB, L1, v1);
        PR(L0, v0);
        const long pA2 = pB + stride;
        LD(pA2, L0, v0);
        PR(L1, v1);
        pA = pA2;
    }
    __syncthreads();
    if (t < NUM_IDS) red[t] = lpull[t] * lcoef[t];
    __syncthreads();
    if (t == 0) {
        float sacc = 0.f;
        for (int cc = 1; cc < NUM_IDS; ++cc) sacc += red[cc];
        atomicAdd(&ws[WS_PULLACC], sacc);
    }
}

__global__ void k5_final(const float* __restrict__ ws, float* __restrict__ out) {
    if (threadIdx.x == 0) {
        float C = ws[WS_C];
        float total = 0.f;
        if (C > 0.f) {
            total = ws[WS_PULLACC] / ws[WS_CF]
                  + ws[WS_PUSH]
                  + 0.001f * ws[WS_REG];
        }
        out[0] = total;
    }
}

extern "C" void kernel_launch(void* const* d_in, const int* in_sizes, int n_in,
                              void* d_out, int out_size, void* d_ws, size_t ws_size,
                              hipStream_t stream) {
    const float4* emb4 = (const float4*)d_in[0];
    const int* lab = (const int*)d_in[1];
    float* ws = (float*)d_ws;
    float* out = (float*)d_out;
    const int M = in_sizes[1];

    long ws_floats = (long)(ws_size / 4);
    long avail = ws_floats - WS_PART - 64;
    int nb1 = (int)(avail / NTOT);
    if (nb1 > 1024) nb1 = 1024;
    int atomic_mode = (nb1 < 8) ? 1 : 0;
    if (atomic_mode) {
        nb1 = 1024;
        k0_zero<<<dim3(9), dim3(256), 0, stream>>>(ws);
    }

    k1_reduce<<<dim3(nb1), dim3(256), 0, stream>>>(emb4, lab, ws, M, nb1, atomic_mode);
    if (!atomic_mode)
        k2_reduce_partials<<<dim3((NTOT + 31) / 32), dim3(256), 0, stream>>>(ws, nb1);
    k3_finalize<<<dim3(1), dim3(256), 0, stream>>>(ws);
    const int nb4 = 2048;
    k4_pull<<<dim3(nb4), dim3(256), 0, stream>>>(emb4, lab, ws, M, nb4);
    k5_final<<<dim3(1), dim3(64), 0, stream>>>(ws, out);
}

// Round 13
// 163.989 us; speedup vs baseline: 3.1510x; 1.0308x over previous
//
#include <hip/hip_runtime.h>

#define NUM_IDS 65
#define EDIM 32
#define NSUM (NUM_IDS * EDIM)      // 2080
#define NTOT (NSUM + NUM_IDS)      // 2145
#define LPAD 33                    // k3 internal tile pad
#define R36 36                     // accum/mean row: 32 sums + count + pad, 144B (16B aligned)
#define CP (NUM_IDS * R36)         // 2340 floats per wave copy

// ws float offsets
#define WS_MEANS   0
#define WS_COEF    2080
#define WS_SUMS    2145
#define WS_PUSH    4290
#define WS_REG     4291
#define WS_CF      4292
#define WS_C       4293
#define WS_PULLACC 4294
#define WS_PART    4352

// pure-VALU cross-lane permute
#define DPPI(x, ctrl) __builtin_amdgcn_update_dpp(0, (x), (ctrl), 0xF, 0xF, true)
// ctrl: 0xB1 quad[1,0,3,2] (^1) | 0x4E quad[2,3,0,1] (^2) | 0x1B quad[3,2,1,0] (^3)
//       0x124 row_ror:4 | 0x141 row_half_mirror

__device__ __forceinline__ void gload4(const float4* p, float4& d) {
    asm volatile("global_load_dwordx4 %0, %1, off" : "=v"(d) : "v"(p));
}
__device__ __forceinline__ void gload1(const int* p, int& d) {
    asm volatile("global_load_dword %0, %1, off" : "=v"(d) : "v"(p));
}
__device__ __forceinline__ void waitN() {      // allow 4 newest loads in flight
    asm volatile("s_waitcnt vmcnt(4)" ::: "memory");
    __builtin_amdgcn_sched_barrier(0);         // rule #18: no hoisting past the wait
}
__device__ __forceinline__ void wait0() {
    asm volatile("s_waitcnt vmcnt(0)" ::: "memory");
    __builtin_amdgcn_sched_barrier(0);
}

__global__ void k0_zero(float* __restrict__ ws) {
    int i = blockIdx.x * 256 + threadIdx.x;
    if (i < NTOT) ws[WS_SUMS + i] = 0.f;
}

// Pass 1: wave-private LDS segment reduction. 8 slots (s=lane&7) x 8 chunks
// (c=lane>>3, float4). Depth-3 asm global-load pipeline (vmcnt-only), DPP
// label butterfly (VALU-only), multi-round exec-masked RMW for duplicates.
__global__ __launch_bounds__(256) void k1_reduce(const float4* __restrict__ emb4,
                                                 const int* __restrict__ lab,
                                                 float* __restrict__ ws,
                                                 int M, int nb1, int nit, int atomic_mode) {
    __shared__ float ls[4 * CP];               // 36.6 KB -> 4 blocks/CU
    const int t = threadIdx.x;
    const int wave = t >> 6, lane = t & 63;
    const int s = lane & 7;                    // point slot
    const int c = lane >> 3;                   // float4 chunk (dims 4c..4c+3)
    float* my = ls + wave * CP;
    for (int j = t; j < 4 * CP; j += 256) ls[j] = 0.f;
    __syncthreads();

    const long Mm1 = (long)M - 1;
    const long STR = (long)nb1 * 32;
    const long p0 = (long)blockIdx.x * 32 + wave * 8 + s;
    const int lp1 = lane + 1;
    int cntreg = 0;
    const int negkey = -64 - s;
    const int e1 = (s ^ 1) < s, e2 = (s ^ 2) < s, e3 = (s ^ 3) < s,
              e4 = (s ^ 4) < s, e5 = (s ^ 5) < s, e6 = (s ^ 6) < s, e7 = (s ^ 7) < s;

    auto ISSUE = [&](int j, int& L, float4& v) {
        long p = p0 + (long)j * STR;
        long pc = p < Mm1 ? p : Mm1;           // clamp: asm loads have no bounds check
        gload1(lab + pc, L);
        gload4(emb4 + pc * 8 + c, v);
    };
    auto PROC = [&](int j, int L, float4 v) {
        const bool inb = (p0 + (long)j * STR) < (long)M;
        const bool act = inb && (L > 0);
        int x0 = act ? L : negkey;             // unique negatives never collide
        int x1 = DPPI(x0, 0xB1);               // key(s^1)
        int x2 = DPPI(x0, 0x4E);               // key(s^2)
        int x3 = DPPI(x1, 0x4E);               // key(s^3)
        int x4 = DPPI(x0, 0x124);              // key(s^4): keys are 8-periodic in lane
        int x5 = DPPI(x1, 0x124);              // key(s^5)
        int x6 = DPPI(x2, 0x124);              // key(s^6)
        int x7 = DPPI(x3, 0x124);              // key(s^7)
        cntreg += (x0 == lp1) + (x1 == lp1) + (x2 == lp1) + (x3 == lp1)
                + (x4 == lp1) + (x5 == lp1) + (x6 == lp1) + (x7 == lp1);
        int ne = (e1 & (x1 == x0)) + (e2 & (x2 == x0)) + (e3 & (x3 == x0))
               + (e4 & (x4 == x0)) + (e5 & (x5 == x0)) + (e6 & (x6 == x0))
               + (e7 & (x7 == x0));            // # earlier slots with same label
        const int off = (act ? L : 0) * R36 + c * 4;
        if (act && ne == 0) {
            float4 o = *(float4*)(my + off);
            o.x += v.x; o.y += v.y; o.z += v.z; o.w += v.w;
            *(float4*)(my + off) = o;
        }
        if (__ballot(act && ne > 0)) {         // rare duplicate labels
            #pragma unroll 1
            for (int r = 1; r < 8; ++r) {
                if (!__ballot(act && ne == r)) break;
                if (act && ne == r) {          // in-order DS sees round r-1 write
                    float4 o = *(float4*)(my + off);
                    o.x += v.x; o.y += v.y; o.z += v.z; o.w += v.w;
                    *(float4*)(my + off) = o;
                }
            }
        }
    };

    int LA, LB, LC; float4 VA, VB, VC;
    ISSUE(0, LA, VA); ISSUE(1, LB, VB);
    for (int i = 0; i < nit; i += 3) {         // nit is a multiple of 3
        ISSUE(i + 2, LC, VC); waitN(); PROC(i, LA, VA);
        ISSUE(i + 3, LA, VA); waitN(); PROC(i + 1, LB, VB);
        ISSUE(i + 4, LB, VB); waitN(); PROC(i + 2, LC, VC);
    }
    wait0();

    my[lp1 * R36 + 32] += (float)cntreg;       // register counts -> rows 1..64
    __syncthreads();

    for (int j = t; j < NTOT; j += 256) {      // combine 4 wave copies
        int off = (j < NSUM) ? ((j >> 5) * R36 + (j & 31))
                             : ((j - NSUM) * R36 + 32);
        float v = ls[off] + ls[CP + off] + ls[2 * CP + off] + ls[3 * CP + off];
        if (atomic_mode) {
            if (v != 0.f) atomicAdd(&ws[WS_SUMS + j], v);
        } else {
            ws[WS_PART + (size_t)blockIdx.x * NTOT + j] = v;
        }
    }
}

__global__ __launch_bounds__(256) void k2_reduce_partials(float* __restrict__ ws, int nb1) {
    const int t = threadIdx.x;
    const int jl = t & 31, bl = t >> 5;
    const int j = blockIdx.x * 32 + jl;
    const float* part = ws + WS_PART;
    float acc = 0.f;
    if (j < NTOT)
        for (int b = bl; b < nb1; b += 8) acc += part[(size_t)b * NTOT + j];
    __shared__ float red[256];
    red[t] = acc;
    __syncthreads();
    for (int sd = 128; sd >= 32; sd >>= 1) {
        if (t < sd) red[t] += red[t + sd];
        __syncthreads();
    }
    if (t < 32) {
        int jj = blockIdx.x * 32 + t;
        if (jj < NTOT) ws[WS_SUMS + jj] = red[t];
    }
}

__global__ __launch_bounds__(256) void k3_finalize(float* __restrict__ ws) {
    __shared__ float lmean[NUM_IDS * LPAD];
    __shared__ float lcnt[NUM_IDS];
    __shared__ int   lpres[NUM_IDS];
    __shared__ float red[256];
    __shared__ float red2[256];
    const int t = threadIdx.x;
    const float* sg = ws + WS_SUMS;

    if (t < NUM_IDS) {
        float cv = sg[NSUM + t];
        lcnt[t] = cv;
        lpres[t] = (t > 0 && cv > 0.f) ? 1 : 0;
    }
    __syncthreads();

    for (int j = t; j < NSUM; j += 256) {
        int cc = j >> 5, e = j & 31;
        float m = sg[j] / fmaxf(lcnt[cc], 1.f);
        ws[WS_MEANS + j] = m;
        lmean[cc * LPAD + e] = m;
    }
    if (t < NUM_IDS) ws[WS_COEF + t] = lpres[t] ? (1.f / fmaxf(lcnt[t], 1.f)) : 0.f;
    __syncthreads();

    float psum = 0.f;
    for (int pi = t; pi < 2080; pi += 256) {
        int i = 0, rem = pi;
        while (rem >= NUM_IDS - 1 - i) { rem -= NUM_IDS - 1 - i; ++i; }
        int jj = i + 1 + rem;
        if (lpres[i] && lpres[jj]) {
            float d2 = 0.f;
            #pragma unroll
            for (int e = 0; e < EDIM; ++e) {
                float d = lmean[i * LPAD + e] - lmean[jj * LPAD + e];
                d2 += d * d;
            }
            float pd = sqrtf(d2);
            float h = fmaxf(3.0f - pd, 0.f);   // 2*DELTA_PUSH
            psum += h * h;
        }
    }
    float rsum = 0.f;
    if (t < NUM_IDS && lpres[t]) {
        float m2 = 0.f;
        #pragma unroll
        for (int e = 0; e < EDIM; ++e) { float m = lmean[t * LPAD + e]; m2 += m * m; }
        rsum = sqrtf(m2);
    }
    red[t] = psum; red2[t] = rsum;
    __syncthreads();
    for (int sd = 128; sd > 0; sd >>= 1) {
        if (t < sd) { red[t] += red[t + sd]; red2[t] += red2[t + sd]; }
        __syncthreads();
    }
    if (t == 0) {
        int C = 0;
        for (int cc = 1; cc < NUM_IDS; ++cc) C += lpres[cc];
        float Cf = fmaxf((float)C, 1.f);
        long np = (long)C * (C - 1) / 2;
        ws[WS_PUSH] = (np > 0) ? red[0] / (float)np : 0.f;
        ws[WS_REG]  = red2[0] / Cf;
        ws[WS_CF]   = Cf;
        ws[WS_C]    = (float)C;
        ws[WS_PULLACC] = 0.f;
    }
}

// Pass 2: pull distances. Linear-coalesced asm loads, depth-3 vmcnt pipeline,
// DPP 8-lane reduction (VALU-only), single b128 mean read per point-lane.
__global__ __launch_bounds__(256) void k4_pull(const float4* __restrict__ emb4,
                                               const int* __restrict__ lab,
                                               float* __restrict__ ws,
                                               int M, int nb4, int nit) {
    __shared__ float lmean[NUM_IDS * R36];     // stride 36 -> b128-aligned rows
    __shared__ float lcoef[NUM_IDS];
    __shared__ float lpull[NUM_IDS];
    __shared__ float red[NUM_IDS];
    const int t = threadIdx.x;
    const int lane = t & 63;
    const int s = lane >> 3, c = lane & 7;     // 8 points x 8 chunk-lanes
    for (int j = t; j < NSUM; j += 256) lmean[(j >> 5) * R36 + (j & 31)] = ws[WS_MEANS + j];
    if (t < NUM_IDS) { lcoef[t] = ws[WS_COEF + t]; lpull[t] = 0.f; }
    __syncthreads();

    const long Mm1 = (long)M - 1;
    const long STR = (long)nb4 * 32;
    const long p0 = (long)blockIdx.x * 32 + (t >> 6) * 8 + s;

    auto ISSUE = [&](int j, int& L, float4& v) {
        long p = p0 + (long)j * STR;
        long pc = p < Mm1 ? p : Mm1;
        gload1(lab + pc, L);
        gload4(emb4 + pc * 8 + c, v);          // lane-linear: fully coalesced
    };
    auto PROC = [&](int j, int L, float4 v) {
        const bool inb = (p0 + (long)j * STR) < (long)M;
        const bool act = inb && (L > 0);
        const float4 mu = *(const float4*)(lmean + L * R36 + c * 4);
        float dx = v.x - mu.x, dy = v.y - mu.y, dz = v.z - mu.z, dw = v.w - mu.w;
        float d2 = act ? (dx * dx + dy * dy + dz * dz + dw * dw) : 0.f;
        int bb;
        bb = DPPI(__float_as_int(d2), 0xB1); d2 += __int_as_float(bb);   // +c^1
        bb = DPPI(__float_as_int(d2), 0x4E); d2 += __int_as_float(bb);   // +c^2
        bb = DPPI(DPPI(__float_as_int(d2), 0x141), 0x1B);                // c^4
        d2 += __int_as_float(bb);
        if (c == 0 && act && d2 > 0.f) {
            float dist = sqrtf(d2);
            float h = fmaxf(dist - 0.5f, 0.f); // DELTA_PULL
            atomicAdd(&lpull[L], h * h);
        }
    };

    int LA, LB, LC; float4 VA, VB, VC;
    ISSUE(0, LA, VA); ISSUE(1, LB, VB);
    for (int i = 0; i < nit; i += 3) {
        ISSUE(i + 2, LC, VC); waitN(); PROC(i, LA, VA);
        ISSUE(i + 3, LA, VA); waitN(); PROC(i + 1, LB, VB);
        ISSUE(i + 4, LB, VB); waitN(); PROC(i + 2, LC, VC);
    }
    wait0();
    __syncthreads();
    if (t < NUM_IDS) red[t] = lpull[t] * lcoef[t];
    __syncthreads();
    if (t == 0) {
        float sacc = 0.f;
        for (int cc = 1; cc < NUM_IDS; ++cc) sacc += red[cc];
        atomicAdd(&ws[WS_PULLACC], sacc);
    }
}

__global__ void k5_final(const float* __restrict__ ws, float* __restrict__ out) {
    if (threadIdx.x == 0) {
        float C = ws[WS_C];
        float total = 0.f;
        if (C > 0.f) {
            total = ws[WS_PULLACC] / ws[WS_CF]
                  + ws[WS_PUSH]
                  + 0.001f * ws[WS_REG];
        }
        out[0] = total;
    }
}

extern "C" void kernel_launch(void* const* d_in, const int* in_sizes, int n_in,
                              void* d_out, int out_size, void* d_ws, size_t ws_size,
                              hipStream_t stream) {
    const float4* emb4 = (const float4*)d_in[0];
    const int* lab = (const int*)d_in[1];
    float* ws = (float*)d_ws;
    float* out = (float*)d_out;
    const int M = in_sizes[1];

    long ws_floats = (long)(ws_size / 4);
    long avail = ws_floats - WS_PART - 64;
    int nb1 = (int)(avail / NTOT);
    if (nb1 > 1024) nb1 = 1024;
    int atomic_mode = (nb1 < 8) ? 1 : 0;
    if (atomic_mode) {
        nb1 = 1024;
        k0_zero<<<dim3(9), dim3(256), 0, stream>>>(ws);
    }
    long str1 = (long)nb1 * 32;
    int nit1 = (int)((M + str1 - 1) / str1);
    nit1 = ((nit1 + 2) / 3) * 3;

    const int nb4 = 2048;
    long str4 = (long)nb4 * 32;
    int nit4 = (int)((M + str4 - 1) / str4);
    nit4 = ((nit4 + 2) / 3) * 3;

    k1_reduce<<<dim3(nb1), dim3(256), 0, stream>>>(emb4, lab, ws, M, nb1, nit1, atomic_mode);
    if (!atomic_mode)
        k2_reduce_partials<<<dim3((NTOT + 31) / 32), dim3(256), 0, stream>>>(ws, nb1);
    k3_finalize<<<dim3(1), dim3(256), 0, stream>>>(ws);
    k4_pull<<<dim3(nb4), dim3(256), 0, stream>>>(emb4, lab, ws, M, nb4, nit4);
    k5_final<<<dim3(1), dim3(64), 0, stream>>>(ws, out);
}